// Round 1
// 250.342 us; speedup vs baseline: 1.0537x; 1.0537x over previous
//
#include <hip/hip_runtime.h>
#include <hip/hip_bf16.h>
#include <stdint.h>

// MMoE: E=16 experts, T=4 tasks, H=512, I=1024, B=8192.
// out[t,b] = sum_e g[b,t,e] * (sum_h relu(x@We^T+be)[b,e,h] * Wf[t,h]) + bf[t]
//
// R14: port moe_main to the 256^2 8-phase counted-vmcnt schedule (T2+T3+T4+T5).
// Previous 128^2 2-barrier structure measured 871 TF = its documented ceiling.
// - 8 waves (512 thr), wave tile 128x64, acc[8][4], BK=64.
// - LDS 128 KiB dynamic: 2 bufs x (A[256][64] | B[256][64]) bf16.
//   Staged by global_load_lds w=16 with pre-swizzled GLOBAL source
//   (chunk c = (l&7)^(l>>3)); ds_read slot = (kh*4+q)^(row&7): 8 distinct
//   rows per bank-group = b128 minimum (conflict-free).
// - Per K-tile 4 phases: {A03+B01 -> q(0,0)} {B23 -> q(0,1)} {A47 -> q(1,1)}
//   {- -> q(1,0)}; 1 half-tile prefetch per phase; raw s_barrier pairs;
//   setprio(1) around MFMA; vmcnt(4) ONLY at phases 4/8 (ledger: 12
//   outstanding, oldest 8 = next tile). Tail peeled, single vmcnt(0).
// - R13 invariant kept: blockIdx.x = mb -> concurrent blocks hit disjoint
//   out rows, no atomic collision.

#define E_ 16
#define T_ 4
#define H_ 512
#define I_ 1024
#define B_ 8192
#define N_ (E_ * H_) /* 8192 */
#define K_ I_        /* 1024 */

typedef __bf16 bf16x8 __attribute__((ext_vector_type(8)));
typedef float f32x4 __attribute__((ext_vector_type(4)));

__device__ __forceinline__ unsigned short f2bf_rne(float f) {
  unsigned int b = __float_as_uint(f);
  b += 0x7fffu + ((b >> 16) & 1u);
  return (unsigned short)(b >> 16);
}

#define N4X (B_ * K_ / 4) /* 2097152 */
#define N4W (N_ * K_ / 4) /* 2097152 */
#define N4G (64 * K_ / 4) /* 16384 */

// merged fp32 -> bf16 (RNE) for x | We | Wg, float4 in / ushort4 out.
// First T_*B_ threads also initialize out[t*B+b] = bf[t] (atomic-accumulated
// by moe_main later; harness re-poisons out before every launch).
__global__ __launch_bounds__(256) void cvt3_kernel(const float* __restrict__ x,
                                                   const float* __restrict__ We,
                                                   const float* __restrict__ Wg,
                                                   const float* __restrict__ bfv,
                                                   unsigned short* __restrict__ xb,
                                                   unsigned short* __restrict__ wb,
                                                   unsigned short* __restrict__ wgb,
                                                   float* __restrict__ out) {
  int i = blockIdx.x * 256 + threadIdx.x;
  if (i < T_ * B_) out[i] = bfv[i >> 13];  // t = i / 8192
  const float* src;
  unsigned short* dst;
  int j;
  if (i < N4X) {
    src = x; dst = xb; j = i;
  } else if (i < N4X + N4W) {
    src = We; dst = wb; j = i - N4X;
  } else if (i < N4X + N4W + N4G) {
    src = Wg; dst = wgb; j = i - (N4X + N4W);
  } else {
    return;
  }
  float4 v = reinterpret_cast<const float4*>(src)[j];
  ushort4 o;
  o.x = f2bf_rne(v.x);
  o.y = f2bf_rne(v.y);
  o.z = f2bf_rne(v.z);
  o.w = f2bf_rne(v.w);
  reinterpret_cast<ushort4*>(dst)[j] = o;
}

__device__ __forceinline__ void gld_lds16(const void* gp, void* lp) {
  __builtin_amdgcn_global_load_lds((const __attribute__((address_space(1))) void*)gp,
                                   (__attribute__((address_space(3))) void*)lp, 16, 0, 0);
}

// logits L[b][te] = x[b,:]@Wg[te,:] + bg[te] via bf16 MFMA (Wg [T][E][I] is
// already B^T [64][1024]), then softmax over e (= the 16 m16-lanes) in
// registers -> g[b][64]. Tile: M=128, N=64, BK=32; 4 waves x 32 rows each.
__global__ __launch_bounds__(256) void logits_softmax_kernel(
    const unsigned short* __restrict__ A,    // x bf16 [B_][K_]
    const unsigned short* __restrict__ Bm,   // Wg bf16 [64][K_]
    const float* __restrict__ bg,            // [64]
    float* __restrict__ g)                   // [B_][64]
{
  __shared__ struct {
    unsigned short A[128 * 32];  // 8 KB
    unsigned short B[64 * 32];   // 4 KB
  } st;

  const int tid = threadIdx.x;
  const int w = tid >> 6, l = tid & 63;
  const int m16 = l & 15, q = l >> 4;
  const size_t m0 = (size_t)blockIdx.x * 128;

  // A staging: rows w*32..w*32+31, 2 chunks/thread
  const int r0s = (w * 2 + 0) * 16 + (l >> 2);
  const int r1s = (w * 2 + 1) * 16 + (l >> 2);
  const int slot = l & 3;
  const int c0 = slot ^ ((r0s >> 1) & 3);
  const int c1 = slot ^ ((r1s >> 1) & 3);
  const size_t offA0 = (m0 + r0s) * K_ + c0 * 8;
  const size_t offA1 = (m0 + r1s) * K_ + c1 * 8;
  const int l0 = (w * 2 + 0) * 512;
  const int l1 = (w * 2 + 1) * 512;
  // B staging: 64 rows, 1 chunk/thread; wave w covers rows w*16..w*16+15
  const int rBs = w * 16 + (l >> 2);
  const int cB = slot ^ ((rBs >> 1) & 3);
  const size_t offB = (size_t)rBs * K_ + cB * 8;
  const int lB = w * 512;

  const int arow = w * 32 + m16;
  const int sA = q ^ ((arow >> 1) & 3);
  const int sB = q ^ ((m16 >> 1) & 3);

  f32x4 acc[2][4] = {};

  for (int k0 = 0; k0 < K_; k0 += 32) {
    __syncthreads();
    gld_lds16(A + offA0 + k0, st.A + l0);
    gld_lds16(A + offA1 + k0, st.A + l1);
    gld_lds16(Bm + offB + k0, st.B + lB);
    __syncthreads();
    bf16x8 af[2], bfr[4];
#pragma unroll
    for (int i = 0; i < 2; ++i)
      af[i] = *reinterpret_cast<const bf16x8*>(st.A + (arow + i * 16) * 32 + sA * 8);
#pragma unroll
    for (int j = 0; j < 4; ++j)
      bfr[j] = *reinterpret_cast<const bf16x8*>(st.B + (j * 16 + m16) * 32 + sB * 8);
#pragma unroll
    for (int i = 0; i < 2; ++i)
#pragma unroll
      for (int j = 0; j < 4; ++j)
        acc[i][j] = __builtin_amdgcn_mfma_f32_16x16x32_bf16(af[i], bfr[j], acc[i][j], 0, 0, 0);
  }

  // acc[i][j][r] = L[row = w*32+16i+4q+r][te = j*16+m16]; t = j, e = m16.
  float bgv[4];
#pragma unroll
  for (int j = 0; j < 4; ++j) bgv[j] = bg[j * 16 + m16];

#pragma unroll
  for (int i = 0; i < 2; ++i) {
    float lg[4][4];  // [r][j]
#pragma unroll
    for (int j = 0; j < 4; ++j)
#pragma unroll
      for (int r = 0; r < 4; ++r) lg[r][j] = acc[i][j][r] + bgv[j];
#pragma unroll
    for (int r = 0; r < 4; ++r) {
#pragma unroll
      for (int j = 0; j < 4; ++j) {
        float m = lg[r][j];
#pragma unroll
        for (int mask = 1; mask < 16; mask <<= 1) m = fmaxf(m, __shfl_xor(m, mask, 64));
        float ex = __expf(lg[r][j] - m);
        float s = ex;
#pragma unroll
        for (int mask = 1; mask < 16; mask <<= 1) s += __shfl_xor(s, mask, 64);
        size_t b = m0 + w * 32 + i * 16 + q * 4 + r;
        g[b * 64 + j * 16 + m16] = ex / s;
      }
    }
  }
}

// ---------------- 256^2 8-phase main kernel ----------------

extern __shared__ char smem[];  // 131072 B: buf d at d*65536; A at +0, B at +32768

#define BARRIER()                          \
  do {                                     \
    asm volatile("" ::: "memory");         \
    __builtin_amdgcn_s_barrier();          \
    asm volatile("" ::: "memory");         \
  } while (0)
#define VMW(n) asm volatile("s_waitcnt vmcnt(" #n ")" ::: "memory")

// stage one half-tile (128 rows x 64 k) of A or B into buf d, half h.
// Each wave covers 16 rows via 2 gld (8 rows / 1024 B each); LDS dest is
// wave-uniform (HW adds lane*16); global src carries the swizzle.
#define STAGE_A(d, h, kk)                                                              \
  do {                                                                                 \
    gld_lds16(A + baseAg + (h)*131072 + (kk), smem + (d)*65536 + (h)*16384 + ldsW);    \
    gld_lds16(A + baseAg + (h)*131072 + 8192 + (kk),                                   \
              smem + (d)*65536 + (h)*16384 + ldsW + 1024);                             \
  } while (0)
#define STAGE_B(d, h, kk)                                                              \
  do {                                                                                 \
    gld_lds16(Bm + baseBg + (h)*131072 + (kk),                                         \
              smem + (d)*65536 + 32768 + (h)*16384 + ldsW);                            \
    gld_lds16(Bm + baseBg + (h)*131072 + 8192 + (kk),                                  \
              smem + (d)*65536 + 32768 + (h)*16384 + ldsW + 1024);                     \
  } while (0)

// ds_read register subtiles (b128, swizzled slot; 8 rows/bank-group minimum)
#define LDA4(d, ib)                                                                       \
  do {                                                                                    \
    _Pragma("unroll") for (int i2 = 0; i2 < 4; ++i2) {                                    \
      af[i2][0] = *reinterpret_cast<const bf16x8*>(smem + (d)*65536 + baseA_rd +          \
                                                   ((ib) + i2) * 2048 + slK0);            \
      af[i2][1] = *reinterpret_cast<const bf16x8*>(smem + (d)*65536 + baseA_rd +          \
                                                   ((ib) + i2) * 2048 + slK1);            \
    }                                                                                     \
  } while (0)
#define LDB2(d, jb)                                                                       \
  do {                                                                                    \
    _Pragma("unroll") for (int j2 = 0; j2 < 2; ++j2) {                                    \
      bfr[(jb) + j2][0] = *reinterpret_cast<const bf16x8*>(smem + (d)*65536 + baseB_rd +  \
                                                           ((jb) + j2) * 2048 + slK0);    \
      bfr[(jb) + j2][1] = *reinterpret_cast<const bf16x8*>(smem + (d)*65536 + baseB_rd +  \
                                                           ((jb) + j2) * 2048 + slK1);    \
    }                                                                                     \
  } while (0)

// one C-quadrant (4 i x 2 j) x K=64: 16 MFMA, setprio-wrapped (T5)
#define MFMAQ(ib, jb)                                                                     \
  do {                                                                                    \
    __builtin_amdgcn_s_setprio(1);                                                        \
    _Pragma("unroll") for (int i2 = 0; i2 < 4; ++i2)                                      \
        _Pragma("unroll") for (int j2 = 0; j2 < 2; ++j2) {                                \
      acc[(ib) + i2][(jb) + j2] = __builtin_amdgcn_mfma_f32_16x16x32_bf16(                \
          af[i2][0], bfr[(jb) + j2][0], acc[(ib) + i2][(jb) + j2], 0, 0, 0);              \
      acc[(ib) + i2][(jb) + j2] = __builtin_amdgcn_mfma_f32_16x16x32_bf16(                \
          af[i2][1], bfr[(jb) + j2][1], acc[(ib) + i2][(jb) + j2], 0, 0, 0);              \
    }                                                                                     \
    __builtin_amdgcn_s_setprio(0);                                                        \
  } while (0)

__global__ __launch_bounds__(512, 2) void moe_main_kernel(
    const unsigned short* __restrict__ A,   // x bf16 [B_][K_]
    const unsigned short* __restrict__ Bm,  // We bf16 [N_][K_]
    const float* __restrict__ be,           // [E_*H_] flat == indexed by n
    const float* __restrict__ Wf,           // [T_][H_]
    const float* __restrict__ g,            // [B_][64] (t*16+e)
    float* __restrict__ out)                // [T_][B_] (pre-init to bf[t])
{
  const int tid = threadIdx.x;
  const int w = tid >> 6, l = tid & 63;
  const int wm = w >> 2, wn = w & 3;  // 2 M-waves x 4 N-waves; wave tile 128x64
  const int m16 = l & 15, q = l >> 4;
  const int mb = blockIdx.x, nb = blockIdx.y;  // x=mb: decorrelate atomics (R13)
  const size_t m0 = (size_t)mb * 256, n0 = (size_t)nb * 256;

  // global staging bases (elements). Row swizzle chunk c = (l&7)^(l>>3).
  const size_t baseAg = (m0 + w * 16 + (l >> 3)) * K_ + (size_t)(((l & 7) ^ (l >> 3)) * 8);
  const size_t baseBg = (n0 + w * 16 + (l >> 3)) * K_ + (size_t)(((l & 7) ^ (l >> 3)) * 8);
  const int ldsW = w * 2048;

  // ds_read addressing: row r at byte r*128; 16B slot (kh*4+q)^(r&7), r&7==m16&7
  const int slK0 = ((q) ^ (m16 & 7)) * 16;
  const int slK1 = ((4 + q) ^ (m16 & 7)) * 16;
  const int baseA_rd = (wm * 128 + m16) * 128;
  const int baseB_rd = 32768 + (wn * 64 + m16) * 128;

  f32x4 acc[8][4] = {};
  bf16x8 af[4][2], bfr[4][2];

  // prologue: tile0 (A+B) -> buf0, tile1 B -> buf1; wait tile0 (8 oldest)
  STAGE_A(0, 0, 0);
  STAGE_A(0, 1, 0);
  STAGE_B(0, 0, 0);
  STAGE_B(0, 1, 0);
  STAGE_B(1, 0, 64);
  STAGE_B(1, 1, 64);
  VMW(4);
  BARRIER();

  // main loop: iteration n computes tiles 2n (buf0), 2n+1 (buf1).
  // Prefetch ledger (per-thread): start with 4 outstanding (tile 2n+1 B).
  // P1..P4 issue 8 more; VMW(4) at P4 completes tile-2n+1 A+B (needed P5).
  // P5..P8 issue 8 more; VMW(4) at P8 completes tile-2n+2 A+B (needed next P1).
#pragma unroll 1
  for (int n = 0; n < 7; ++n) {
    const int kA1 = (2 * n + 1) * 64;  // tile 2n+1 (A halves)
    const int kN2 = (2 * n + 2) * 64;  // tile 2n+2 (full, into buf0)
    const int kB3 = (2 * n + 3) * 64;  // tile 2n+3 (B halves, into buf1)
    // P1
    LDA4(0, 0); LDB2(0, 0); STAGE_A(1, 0, kA1);
    BARRIER(); MFMAQ(0, 0); BARRIER();
    // P2
    LDB2(0, 2); STAGE_A(1, 1, kA1);
    BARRIER(); MFMAQ(0, 2); BARRIER();
    // P3
    LDA4(0, 4); STAGE_B(0, 0, kN2);
    BARRIER(); MFMAQ(4, 2); BARRIER();
    // P4
    STAGE_B(0, 1, kN2); VMW(4);
    BARRIER(); MFMAQ(4, 0); BARRIER();
    // P5
    LDA4(1, 0); LDB2(1, 0); STAGE_A(0, 0, kN2);
    BARRIER(); MFMAQ(0, 0); BARRIER();
    // P6
    LDB2(1, 2); STAGE_A(0, 1, kN2);
    BARRIER(); MFMAQ(0, 2); BARRIER();
    // P7
    LDA4(1, 4); STAGE_B(1, 0, kB3);
    BARRIER(); MFMAQ(4, 2); BARRIER();
    // P8
    STAGE_B(1, 1, kB3); VMW(4);
    BARRIER(); MFMAQ(4, 0); BARRIER();
  }

  // tail: tiles 14 (buf0), 15 (buf1). Stage tile15 A, single vmcnt(0) drain.
  LDA4(0, 0); LDB2(0, 0); STAGE_A(1, 0, 15 * 64);
  BARRIER(); MFMAQ(0, 0); BARRIER();
  LDB2(0, 2); STAGE_A(1, 1, 15 * 64);
  BARRIER(); MFMAQ(0, 2); BARRIER();
  LDA4(0, 4);
  BARRIER(); MFMAQ(4, 2); BARRIER();
  VMW(0);
  BARRIER(); MFMAQ(4, 0); BARRIER();
  LDA4(1, 0); LDB2(1, 0);
  BARRIER(); MFMAQ(0, 0); BARRIER();
  LDB2(1, 2);
  BARRIER(); MFMAQ(0, 2); BARRIER();
  LDA4(1, 4);
  BARRIER(); MFMAQ(4, 2); BARRIER();
  MFMAQ(4, 0);

  // ---- epilogue: relu+bias, Wf contraction, butterfly, cross-wn combine ----
  // staging LDS dead (last read T7, barrier passed); reuse as allsums[4][1024].
  float* allsums = (float*)smem;

  const int hb = (int)(n0 & 511);      // h-offset of this tile
  const int e_idx = (int)(n0 >> 9);    // expert (256-wide tile never crosses)

  float wfv[4][4];  // [t][j]
#pragma unroll
  for (int t = 0; t < 4; ++t)
#pragma unroll
    for (int j = 0; j < 4; ++j)
      wfv[t][j] = Wf[t * H_ + hb + wn * 64 + j * 16 + m16];
  float bias[4];
#pragma unroll
  for (int j = 0; j < 4; ++j) bias[j] = be[n0 + wn * 64 + j * 16 + m16];

  const int b0s = m16 & 1, b1s = (m16 >> 1) & 1, b2s = (m16 >> 2) & 1, b3s = (m16 >> 3) & 1;
#pragma unroll
  for (int i = 0; i < 8; ++i) {
    float eo[4][4];  // [j][reg]
#pragma unroll
    for (int j = 0; j < 4; ++j)
#pragma unroll
      for (int r = 0; r < 4; ++r) eo[j][r] = fmaxf(acc[i][j][r] + bias[j], 0.f);
    float p[16];  // slot s = reg*4 + t, partial over this lane's 4 cols
#pragma unroll
    for (int r = 0; r < 4; ++r)
#pragma unroll
      for (int t = 0; t < 4; ++t) {
        float v = 0.f;
#pragma unroll
        for (int j = 0; j < 4; ++j) v += eo[j][r] * wfv[t][j];
        p[r * 4 + t] = v;
      }
    // Compacting fold-exchange butterfly over the 16 m16-lanes.
    float q8[8];
#pragma unroll
    for (int m = 0; m < 8; ++m) {
      float sent = b0s ? p[2 * m] : p[2 * m + 1];
      float recv = __shfl_xor(sent, 1, 64);
      q8[m] = (b0s ? p[2 * m + 1] : p[2 * m]) + recv;
    }
    float q4[4];
#pragma unroll
    for (int u = 0; u < 4; ++u) {
      float sent = b1s ? q8[2 * u] : q8[2 * u + 1];
      float recv = __shfl_xor(sent, 2, 64);
      q4[u] = (b1s ? q8[2 * u + 1] : q8[2 * u]) + recv;
    }
    float q2[2];
#pragma unroll
    for (int u = 0; u < 2; ++u) {
      float sent = b2s ? q4[2 * u] : q4[2 * u + 1];
      float recv = __shfl_xor(sent, 4, 64);
      q2[u] = (b2s ? q4[2 * u + 1] : q4[2 * u]) + recv;
    }
    float sent = b3s ? q2[0] : q2[1];
    float recv = __shfl_xor(sent, 8, 64);
    float v = (b3s ? q2[1] : q2[0]) + recv;  // slot == m16

    int row = wm * 128 + i * 16 + q * 4 + (m16 >> 2);  // reg_sel = m16>>2
    allsums[wn * 1024 + row * 4 + (m16 & 3)] = v;      // t_sel = m16&3
  }
  __syncthreads();

  // combine the 4 wn-quarters, apply gate, atomic-accumulate into out.
  {
    float2 s = *reinterpret_cast<float2*>(&allsums[0 * 1024 + tid * 2]);
    float2 x1 = *reinterpret_cast<float2*>(&allsums[1 * 1024 + tid * 2]);
    float2 x2 = *reinterpret_cast<float2*>(&allsums[2 * 1024 + tid * 2]);
    float2 x3 = *reinterpret_cast<float2*>(&allsums[3 * 1024 + tid * 2]);
    s.x += x1.x + x2.x + x3.x;
    s.y += x1.y + x2.y + x3.y;
#pragma unroll
    for (int oi = 0; oi < 2; ++oi) {
      int o = tid * 2 + oi;
      int row = o >> 2, t = o & 3;
      float sv = oi ? s.y : s.x;
      size_t b = m0 + row;
      float gv = g[b * 64 + t * 16 + e_idx];
      atomicAdd(&out[(size_t)t * B_ + b], gv * sv);
    }
  }
}

extern "C" void kernel_launch(void* const* d_in, const int* in_sizes, int n_in,
                              void* d_out, int out_size, void* d_ws, size_t ws_size,
                              hipStream_t stream) {
  const float* x = (const float*)d_in[0];   // [B, I]
  const float* We = (const float*)d_in[1];  // [E, H, I]
  const float* be = (const float*)d_in[2];  // [E, H]
  const float* Wg = (const float*)d_in[3];  // [T, E, I]
  const float* bg = (const float*)d_in[4];  // [T, E]
  const float* Wf = (const float*)d_in[5];  // [T, H]
  const float* bf = (const float*)d_in[6];  // [T]
  float* out = (float*)d_out;               // [T, B, 1]

  // ws: xb (16.8MB) | wb (16.8MB) | wgb (0.13MB) | g (2.1MB)
  unsigned short* xb = (unsigned short*)d_ws;
  unsigned short* wb = xb + (size_t)B_ * K_;
  unsigned short* wgb = wb + (size_t)N_ * K_;
  float* g = (float*)(wgb + (size_t)64 * K_);

  // opt-in for 128 KiB dynamic LDS (host-side, not a stream op: capture-safe)
  hipFuncSetAttribute((const void*)moe_main_kernel,
                      hipFuncAttributeMaxDynamicSharedMemorySize, 131072);

  cvt3_kernel<<<(N4X + N4W + N4G + 255) / 256, 256, 0, stream>>>(x, We, Wg, bf, xb, wb, wgb, out);
  logits_softmax_kernel<<<B_ / 128, 256, 0, stream>>>(xb, wgb, bg, g);
  dim3 grid(B_ / 256, N_ / 256);  // x = mb (disjoint out rows among concurrent blocks)
  moe_main_kernel<<<grid, 512, 131072, stream>>>(xb, wb, be, Wf, g, out);
}